// Round 15
// baseline (345.119 us; speedup 1.0000x reference)
//
#include <hip/hip_runtime.h>

// Problem constants (fixed by reference)
#define N_NODES 50000
#define E_EDGES 800000
#define BN_EPS 1e-5f
#define SLOPE 0.01f

#define SCAN_CHUNK 2048
#define SCAN_BLOCKS ((N_NODES + SCAN_CHUNK - 1) / SCAN_CHUNK)   // 25
#define STAT_SHARDS 32
#define FILL_PASSES 8

typedef unsigned short ushort_t;
typedef unsigned int uint_t;
typedef short short8 __attribute__((ext_vector_type(8)));
typedef float floatx4 __attribute__((ext_vector_type(4)));

__device__ __forceinline__ float ulo(uint_t v) { return __uint_as_float(v << 16); }
__device__ __forceinline__ float uhi(uint_t v) { return __uint_as_float(v & 0xffff0000u); }
__device__ __forceinline__ ushort_t f2b(float f) {   // round-to-nearest-even
    uint_t u = __float_as_uint(f);
    return (ushort_t)((u + 0x7fffu + ((u >> 16) & 1u)) >> 16);
}
__device__ __forceinline__ uint_t pack2(float a, float b) {
    return (uint_t)f2b(a) | ((uint_t)f2b(b) << 16);
}

// bf16 weight buffer offsets (elements)
#define OWA0 0
#define OWB0 16384
#define OWA1 24576
#define OWB1 28672
#define OWA2 32768
#define OWB2 36864
#define OFC1 40960
#define WTOT 61440
#define CVT_BLOCKS ((WTOT + 255) / 256)       // 240
#define P_BLOCKS 48                           // 96*128/256
#define X0_BLOCKS ((N_NODES * 64 + 255) / 256)   // 12500
#define E_BLOCKS ((E_EDGES + 255) / 256)         // 3125
#define STATZ_BLOCKS 16                          // 16384 floats / (256*4)

// ---------------------------------------------------------------------------
// K-front: fused front-end. Block ranges:
//  [0, 240)                weight fp32->bf16 convert
//  [240, 288)              Pt[128,96]: Pt[j,c]=dot(dict_c, wa0_j); c>=80 -> 0
//  [288, 288+12500)        build x0 (bf16) + ncls
//  [.., +3125)             degrank: rank[e]=atomicAdd(&deg[dst],1)  (cdeg pre-zeroed)
//  [.., +16)               zero the 4*32*128 stat buffer
// ---------------------------------------------------------------------------
__global__ void k_front(const float* __restrict__ wa0, const float* __restrict__ wb0,
                        const float* __restrict__ wa1, const float* __restrict__ wb1,
                        const float* __restrict__ wa2, const float* __restrict__ wb2,
                        const float* __restrict__ fc1w, ushort_t* __restrict__ wdst,
                        const float* __restrict__ ed, const float* __restrict__ el,
                        ushort_t* __restrict__ Pt,
                        const int* __restrict__ nd, const int* __restrict__ nl,
                        uint_t* __restrict__ x0u, int* __restrict__ ncls,
                        const int* __restrict__ dst, int* __restrict__ deg,
                        int* __restrict__ rank, float* __restrict__ stat) {
    int b = blockIdx.x, t = threadIdx.x;
    if (b < CVT_BLOCKS) {
        int i = b * 256 + t;
        if (i >= WTOT) return;
        float v;
        if      (i < OWB0) v = wa0[i];
        else if (i < OWA1) v = wb0[i - OWB0];
        else if (i < OWB1) v = wa1[i - OWA1];
        else if (i < OWA2) v = wb1[i - OWB1];
        else if (i < OWB2) v = wa2[i - OWB2 + OWA2 - OWA2];  // == wa2[i-OWA2]
        else if (i < OFC1) v = wb2[i - OWB2];
        else               v = fc1w[i - OFC1];
        // fix the wa2 branch arithmetic explicitly:
        if (i >= OWA2 && i < OWB2) v = wa2[i - OWA2];
        wdst[i] = f2b(v);
    } else if (b < CVT_BLOCKS + P_BLOCKS) {
        int pid = (b - CVT_BLOCKS) * 256 + t;   // c*128 + j over 96*128
        int c = pid >> 7, j = pid & 127;
        float acc = 0.f;
        if (c < 64) {
            const float* dr = ed + c * 64;
            const float* wr = wa0 + (size_t)j * 128;
            #pragma unroll 8
            for (int k = 0; k < 64; ++k) acc += dr[k] * wr[k];
        } else if (c < 80) {
            const float* dr = el + (c - 64) * 64;
            const float* wr = wa0 + (size_t)j * 128 + 64;
            #pragma unroll 8
            for (int k = 0; k < 64; ++k) acc += dr[k] * wr[k];
        }
        Pt[(size_t)j * 96 + c] = f2b(acc);
    } else if (b < CVT_BLOCKS + P_BLOCKS + X0_BLOCKS) {
        int idx = (b - CVT_BLOCKS - P_BLOCKS) * 256 + t;  // N*64 uint slots
        if (idx >= N_NODES * 64) return;
        int n = idx >> 6, c = idx & 63;
        int d = nd[n], l = nl[n];
        if (c == 0) ncls[n] = d | (l << 16);
        float2 v = (c < 32) ? *(const float2*)(ed + d * 64 + c * 2)
                            : *(const float2*)(el + l * 64 + (c - 32) * 2);
        x0u[(size_t)n * 64 + c] = pack2(v.x, v.y);
    } else if (b < CVT_BLOCKS + P_BLOCKS + X0_BLOCKS + E_BLOCKS) {
        int e = (b - CVT_BLOCKS - P_BLOCKS - X0_BLOCKS) * 256 + t;
        if (e >= E_EDGES) return;
        rank[e] = atomicAdd(&deg[dst[e]], 1);
    } else {
        int idx = (b - CVT_BLOCKS - P_BLOCKS - X0_BLOCKS - E_BLOCKS) * 256 + t;
        if (idx < 4096)
            *(float4*)(stat + (size_t)idx * 4) = make_float4(0.f, 0.f, 0.f, 0.f);
    }
}

// ---------------------------------------------------------------------------
// K-scan: single-kernel exclusive scan. Block b sums deg[0..b*2048) itself
// for its cross-block offset, then local Hillis-Steele over its chunk.
// ---------------------------------------------------------------------------
__global__ __launch_bounds__(256) void k_scan(const int* __restrict__ deg,
                                              int* __restrict__ rowptr) {
    __shared__ int part[256];
    __shared__ int bofs_sh;
    int t = threadIdx.x, b = blockIdx.x;
    // cross-block offset: sum of preceding chunks
    int pre = 0;
    int lim = b * SCAN_CHUNK;
    for (int i = t; i < lim; i += 256) pre += deg[i];
    part[t] = pre;
    __syncthreads();
    #pragma unroll
    for (int off = 128; off; off >>= 1) {
        if (t < off) part[t] += part[t + off];
        __syncthreads();
    }
    if (t == 0) bofs_sh = part[0];
    __syncthreads();
    int bofs = bofs_sh;
    __syncthreads();                    // part[] about to be reused
    // local scan over this chunk
    int base = b * SCAN_CHUNK + t * 8;
    int vals[8];
    int s = 0;
    #pragma unroll
    for (int i = 0; i < 8; ++i) {
        int idx = base + i;
        vals[i] = (idx < N_NODES) ? deg[idx] : 0;
        s += vals[i];
    }
    part[t] = s;
    __syncthreads();
    #pragma unroll
    for (int off = 1; off < 256; off <<= 1) {
        int v = (t >= off) ? part[t - off] : 0;
        __syncthreads();
        part[t] += v;
        __syncthreads();
    }
    int run = bofs + part[t] - s;
    #pragma unroll
    for (int i = 0; i < 8; ++i) {
        int idx = base + i;
        if (idx < N_NODES) {
            rowptr[idx] = run;
            run += vals[i];
        }
    }
}

// k_fill: 8 dst-range passes; pass-p blocks adjacent in dispatch order so the
// write window stays L2-hot. No atomics (rank precomputed).
// epk record: src(16b) | deg(6b)<<16 | lab(4b)<<22
__global__ void k_fill(const int* __restrict__ src, const int* __restrict__ dst,
                       const int* __restrict__ ncls, const int* __restrict__ rowptr,
                       const int* __restrict__ rank, int* __restrict__ epk,
                       int blocks_per_pass) {
    int p = blockIdx.x / blocks_per_pass;
    int e = (blockIdx.x % blocks_per_pass) * blockDim.x + threadIdx.x;
    if (e >= E_EDGES) return;
    int d = dst[e];
    const int span = (N_NODES + FILL_PASSES - 1) / FILL_PASSES;   // 6250
    int lo = p * span;
    if (d < lo || d >= lo + span) return;
    int s = src[e];
    int c = ncls[s];
    epk[rowptr[d] + rank[e]] = s | ((c & 63) << 16) | ((c >> 16) << 22);
}

// ---------------------------------------------------------------------------
// K-mlp0: layer 0. LDS class histogram (1 lane/edge) + dense MFMA.
// ---------------------------------------------------------------------------
__global__ __launch_bounds__(256, 8) void k_mlp0(
        const int* __restrict__ rowptr, const int* __restrict__ cdeg,
        const int* __restrict__ epk, const int* __restrict__ ncls,
        const ushort_t* __restrict__ Pt, const float* __restrict__ ba,
        const ushort_t* __restrict__ wbB, const float* __restrict__ bb,
        float* __restrict__ ybuf, float* __restrict__ stat_l) {
    constexpr int LHS = 98;
    constexpr int LDC = 104;
    constexpr int LDH = 136;
    __shared__ int hist[16 * LHS];
    __shared__ ushort_t xs[16 * LDC];
    __shared__ ushort_t hs[16 * LDH];
    uint_t* xsu = (uint_t*)xs;
    int t = threadIdx.x;
    int row0 = blockIdx.x * 16;
    int lane = t & 63, wv = t >> 6;
    int half = lane >> 5, hl = lane & 31;

    for (int i = t; i < 16 * LHS; i += 256) hist[i] = 0;
    __syncthreads();

    for (int i = 0; i < 2; ++i) {
        int lr = wv * 4 + i * 2 + half, node = row0 + lr;
        if (node < N_NODES) {
            if (hl == 0) {
                int c = ncls[node];
                atomicAdd(&hist[lr * LHS + (c & 0xffff)], 1);
                atomicAdd(&hist[lr * LHS + 64 + (c >> 16)], 1);
            }
            int start = rowptr[node], n = cdeg[node];
            for (int j0 = 0; j0 < n; j0 += 32) {
                int m = n - j0; if (m > 32) m = 32;
                if (hl < m) {
                    int ev = epk[start + j0 + hl];
                    atomicAdd(&hist[lr * LHS + ((ev >> 16) & 63)], 1);
                    atomicAdd(&hist[lr * LHS + 64 + ((ev >> 22) & 15)], 1);
                }
            }
        }
    }
    __syncthreads();

    for (int i = t; i < 16 * 48; i += 256) {
        int row = i / 48, c2 = i % 48;
        uint_t v = 0;
        if (c2 < 40)
            v = pack2((float)hist[row * LHS + c2 * 2],
                      (float)hist[row * LHS + c2 * 2 + 1]);
        xsu[row * 52 + c2] = v;
    }
    __syncthreads();

    int m = lane & 15, quad = lane >> 4;

    // ---- lin1 (MFMA, K=96) + lrelu -> hs
    {
        floatx4 acc[2];
        acc[0] = (floatx4){0.f, 0.f, 0.f, 0.f};
        acc[1] = (floatx4){0.f, 0.f, 0.f, 0.f};
        #pragma unroll
        for (int ks = 0; ks < 3; ++ks) {
            short8 af = *(const short8*)(xs + m * LDC + ks * 32 + quad * 8);
            #pragma unroll
            for (int g = 0; g < 2; ++g) {
                int col = (wv * 2 + g) * 16 + m;
                short8 bf = *(const short8*)(Pt + (size_t)col * 96 + ks * 32 + quad * 8);
                acc[g] = __builtin_amdgcn_mfma_f32_16x16x32_bf16(af, bf, acc[g], 0, 0, 0);
            }
        }
        #pragma unroll
        for (int g = 0; g < 2; ++g) {
            int col = (wv * 2 + g) * 16 + m;
            float bias = ba[col];
            #pragma unroll
            for (int r = 0; r < 4; ++r) {
                float v = acc[g][r] + bias;
                v = v > 0.f ? v : SLOPE * v;
                hs[(quad * 4 + r) * LDH + col] = f2b(v);
            }
        }
    }
    __syncthreads();

    // ---- lin2 (MFMA, K=128)
    {
        floatx4 acc = (floatx4){0.f, 0.f, 0.f, 0.f};
        int col = wv * 16 + m;
        #pragma unroll
        for (int ks = 0; ks < 4; ++ks) {
            short8 af = *(const short8*)(hs + m * LDH + ks * 32 + quad * 8);
            short8 bf = *(const short8*)(wbB + (size_t)col * 128 + ks * 32 + quad * 8);
            acc = __builtin_amdgcn_mfma_f32_16x16x32_bf16(af, bf, acc, 0, 0, 0);
        }
        float bias = bb[col];
        float ps = 0.f, pq = 0.f;
        #pragma unroll
        for (int r = 0; r < 4; ++r) {
            int node = row0 + quad * 4 + r;
            float v = acc[r] + bias;
            if (node < N_NODES) ybuf[(size_t)node * 64 + col] = v;
            else v = 0.f;
            ps += v; pq += v * v;
        }
        ps += __shfl_xor(ps, 16); pq += __shfl_xor(pq, 16);
        ps += __shfl_xor(ps, 32); pq += __shfl_xor(pq, 32);
        if (quad == 0) {
            float* st = stat_l + (blockIdx.x & (STAT_SHARDS - 1)) * 128;
            atomicAdd(&st[col], ps);
            atomicAdd(&st[64 + col], pq);
        }
    }
}

// ---------------------------------------------------------------------------
// K2: layers 1,2 (D=64). Gather via uint4 row segments: 8 lanes x 16B cover a
// 128B row; one load fetches 4 edges' rows. Remainder-loop __shfl hoisted out
// of the predicate (shfl source lanes must be active — R13 bug).
// ---------------------------------------------------------------------------
__global__ __launch_bounds__(256, 8) void k_mlp64(
        const ushort_t* __restrict__ xb,
        const int* __restrict__ rowptr, const int* __restrict__ cdeg,
        const int* __restrict__ epk,
        const ushort_t* __restrict__ waB, const float* __restrict__ ba,
        const ushort_t* __restrict__ wbB, const float* __restrict__ bb,
        float* __restrict__ ybuf, float* __restrict__ stat_l) {
    constexpr int LDWB = 72;   // ushorts; row stride 144B (16B multiple)
    __shared__ ushort_t xs[16 * LDWB];
    __shared__ ushort_t hs[16 * LDWB];
    int t = threadIdx.x;
    int row0 = blockIdx.x * 16;
    int lane = t & 63, wv = t >> 6;
    int half = lane >> 5, hl = lane & 31;
    int g = hl >> 3, sseg = hl & 7;           // edge-group, 16B row segment
    const uint4* xu4 = (const uint4*)xb;      // row = 8 uint4

    for (int i = 0; i < 2; ++i) {
        int lr = wv * 4 + i * 2 + half, node = row0 + lr;
        float acc[8] = {0.f, 0.f, 0.f, 0.f, 0.f, 0.f, 0.f, 0.f};
        if (node < N_NODES) {
            int start = rowptr[node], n = cdeg[node];
            if (g == 0) {   // self row (group 0 lanes)
                uint4 v = xu4[(size_t)node * 8 + sseg];
                acc[0] += ulo(v.x); acc[1] += uhi(v.x);
                acc[2] += ulo(v.y); acc[3] += uhi(v.y);
                acc[4] += ulo(v.z); acc[5] += uhi(v.z);
                acc[6] += ulo(v.w); acc[7] += uhi(v.w);
            }
            for (int j0 = 0; j0 < n; j0 += 32) {
                int m = n - j0; if (m > 32) m = 32;
                int ev = (hl < m) ? epk[start + j0 + hl] : 0;
                int j = 0;
                for (; j + 8 <= m; j += 8) {
                    int sa = __shfl(ev, j + g, 32) & 0xffff;
                    int sb = __shfl(ev, j + 4 + g, 32) & 0xffff;
                    uint4 va = xu4[(size_t)sa * 8 + sseg];
                    uint4 vb = xu4[(size_t)sb * 8 + sseg];
                    acc[0] += ulo(va.x); acc[1] += uhi(va.x);
                    acc[2] += ulo(va.y); acc[3] += uhi(va.y);
                    acc[4] += ulo(va.z); acc[5] += uhi(va.z);
                    acc[6] += ulo(va.w); acc[7] += uhi(va.w);
                    acc[0] += ulo(vb.x); acc[1] += uhi(vb.x);
                    acc[2] += ulo(vb.y); acc[3] += uhi(vb.y);
                    acc[4] += ulo(vb.z); acc[5] += uhi(vb.z);
                    acc[6] += ulo(vb.w); acc[7] += uhi(vb.w);
                }
                for (; j < m; j += 4) {
                    int sa = __shfl(ev, j + g, 32) & 0xffff;  // all lanes exec
                    if (g < m - j) {
                        uint4 va = xu4[(size_t)sa * 8 + sseg];
                        acc[0] += ulo(va.x); acc[1] += uhi(va.x);
                        acc[2] += ulo(va.y); acc[3] += uhi(va.y);
                        acc[4] += ulo(va.z); acc[5] += uhi(va.z);
                        acc[6] += ulo(va.w); acc[7] += uhi(va.w);
                    }
                }
            }
        }
        #pragma unroll
        for (int q = 0; q < 8; ++q) {
            acc[q] += __shfl_xor(acc[q], 8, 32);
            acc[q] += __shfl_xor(acc[q], 16, 32);
        }
        if (g == 0) {
            uint4 pv = make_uint4(pack2(acc[0], acc[1]), pack2(acc[2], acc[3]),
                                  pack2(acc[4], acc[5]), pack2(acc[6], acc[7]));
            *(uint4*)(xs + lr * LDWB + sseg * 8) = pv;
        }
    }
    __syncthreads();

    int m = lane & 15, quad = lane >> 4;

    // ---- lin1 (MFMA) + lrelu -> hs
    {
        floatx4 acc = (floatx4){0.f, 0.f, 0.f, 0.f};
        int col = wv * 16 + m;
        #pragma unroll
        for (int ks = 0; ks < 2; ++ks) {
            short8 af = *(const short8*)(xs + m * LDWB + ks * 32 + quad * 8);
            short8 bf = *(const short8*)(waB + (size_t)col * 64 + ks * 32 + quad * 8);
            acc = __builtin_amdgcn_mfma_f32_16x16x32_bf16(af, bf, acc, 0, 0, 0);
        }
        float bias = ba[col];
        #pragma unroll
        for (int r = 0; r < 4; ++r) {
            float v = acc[r] + bias;
            v = v > 0.f ? v : SLOPE * v;
            hs[(quad * 4 + r) * LDWB + col] = f2b(v);
        }
    }
    __syncthreads();

    // ---- lin2 (MFMA)
    {
        floatx4 acc = (floatx4){0.f, 0.f, 0.f, 0.f};
        int col = wv * 16 + m;
        #pragma unroll
        for (int ks = 0; ks < 2; ++ks) {
            short8 af = *(const short8*)(hs + m * LDWB + ks * 32 + quad * 8);
            short8 bf = *(const short8*)(wbB + (size_t)col * 64 + ks * 32 + quad * 8);
            acc = __builtin_amdgcn_mfma_f32_16x16x32_bf16(af, bf, acc, 0, 0, 0);
        }
        float bias = bb[col];
        float ps = 0.f, pq = 0.f;
        #pragma unroll
        for (int r = 0; r < 4; ++r) {
            int node = row0 + quad * 4 + r;
            float v = acc[r] + bias;
            if (node < N_NODES) ybuf[(size_t)node * 64 + col] = v;
            else v = 0.f;
            ps += v; pq += v * v;
        }
        ps += __shfl_xor(ps, 16); pq += __shfl_xor(pq, 16);
        ps += __shfl_xor(ps, 32); pq += __shfl_xor(pq, 32);
        if (quad == 0) {
            float* st = stat_l + (blockIdx.x & (STAT_SHARDS - 1)) * 128;
            atomicAdd(&st[col], ps);
            atomicAdd(&st[64 + col], pq);
        }
    }
}

// ---------------------------------------------------------------------------
// K4: x_out(bf16) = lrelu(y*scale + shift); stats summed over shards
// ---------------------------------------------------------------------------
__global__ void k_bn_apply(const float* __restrict__ y, const float* __restrict__ stat_l,
                           const float* __restrict__ gw, const float* __restrict__ gb,
                           uint_t* __restrict__ xo) {
    __shared__ float sc[64], sh[64];
    int t = threadIdx.x;
    if (t < 64) {
        float s0 = 0.f, q0 = 0.f;
        #pragma unroll
        for (int j = 0; j < STAT_SHARDS; ++j) {
            s0 += stat_l[j * 128 + t];
            q0 += stat_l[j * 128 + 64 + t];
        }
        float mmm = s0 * (1.0f / N_NODES);
        float var = q0 * (1.0f / N_NODES) - mmm * mmm;
        float s = gw[t] * rsqrtf(var + BN_EPS);
        sc[t] = s; sh[t] = gb[t] - mmm * s;
    }
    __syncthreads();
    int idx = blockIdx.x * blockDim.x + t;    // N*16 float4 slots
    if (idx >= N_NODES * 16) return;
    int c4 = (idx & 15) * 4;
    float4 v4 = *(const float4*)(y + (size_t)idx * 4);
    float o0 = v4.x * sc[c4]     + sh[c4];     o0 = o0 > 0.f ? o0 : SLOPE * o0;
    float o1 = v4.y * sc[c4 + 1] + sh[c4 + 1]; o1 = o1 > 0.f ? o1 : SLOPE * o1;
    float o2 = v4.z * sc[c4 + 2] + sh[c4 + 2]; o2 = o2 > 0.f ? o2 : SLOPE * o2;
    float o3 = v4.w * sc[c4 + 3] + sh[c4 + 3]; o3 = o3 > 0.f ? o3 : SLOPE * o3;
    xo[(size_t)idx * 2]     = pack2(o0, o1);
    xo[(size_t)idx * 2 + 1] = pack2(o2, o3);
}

// ---------------------------------------------------------------------------
// K5: fc1 (MFMA), K=320. x3 segment computed INLINE from ybuf (layer-2 pre-BN)
// + stat2 — deletes the third bn_apply. Each block reads/writes only its own
// 16 ybuf rows (stage-then-overwrite, no cross-block hazard).
// ---------------------------------------------------------------------------
__global__ __launch_bounds__(256, 8) void k_fc1(
        const uint_t* __restrict__ x0u, const uint_t* __restrict__ x1u,
        const uint_t* __restrict__ x2u, const float* __restrict__ ybuf_in,
        const float* __restrict__ stat2,
        const float* __restrict__ gw2, const float* __restrict__ gb2,
        const ushort_t* __restrict__ wB, const float* __restrict__ b,
        float* __restrict__ ybuf, float* __restrict__ stat_l) {
    constexpr int LDWB = 328;            // ushort stride (320+8), /2=164 uints
    __shared__ ushort_t xs[16 * LDWB];
    __shared__ float sc2[64], sh2[64];
    uint_t* xsu = (uint_t*)xs;
    int t = threadIdx.x;
    int row0 = blockIdx.x * 16;

    if (t < 64) {   // layer-2 BN coefficients from sharded stats
        float s0 = 0.f, q0 = 0.f;
        #pragma unroll
        for (int j = 0; j < STAT_SHARDS; ++j) {
            s0 += stat2[j * 128 + t];
            q0 += stat2[j * 128 + 64 + t];
        }
        float mmm = s0 * (1.0f / N_NODES);
        float var = q0 * (1.0f / N_NODES) - mmm * mmm;
        float s = gw2[t] * rsqrtf(var + BN_EPS);
        sc2[t] = s; sh2[t] = gb2[t] - mmm * s;
    }
    __syncthreads();

    for (int i = t; i < 16 * 160; i += 256) {
        int row = i / 160, c = i % 160;
        int g = row0 + row;
        uint_t v = 0;
        if (g < N_NODES) {
            if      (c < 64)  v = x0u[(size_t)g * 64 + c];
            else if (c < 96)  v = x1u[(size_t)g * 32 + (c - 64)];
            else if (c < 128) v = x2u[(size_t)g * 32 + (c - 96)];
            else {
                int cc = (c - 128) * 2;
                float2 yv = *(const float2*)(ybuf_in + (size_t)g * 64 + cc);
                float o0 = yv.x * sc2[cc]     + sh2[cc];
                float o1 = yv.y * sc2[cc + 1] + sh2[cc + 1];
                o0 = o0 > 0.f ? o0 : SLOPE * o0;
                o1 = o1 > 0.f ? o1 : SLOPE * o1;
                v = pack2(o0, o1);
            }
        }
        xsu[row * 164 + c] = v;
    }
    __syncthreads();

    int lane = t & 63, wv = t >> 6;
    int m = lane & 15, quad = lane >> 4;
    int col = wv * 16 + m;
    floatx4 acc = (floatx4){0.f, 0.f, 0.f, 0.f};
    #pragma unroll
    for (int ks = 0; ks < 10; ++ks) {
        short8 af = *(const short8*)(xs + m * LDWB + ks * 32 + quad * 8);
        short8 bf = *(const short8*)(wB + (size_t)col * 320 + ks * 32 + quad * 8);
        acc = __builtin_amdgcn_mfma_f32_16x16x32_bf16(af, bf, acc, 0, 0, 0);
    }
    float bias = b[col];
    float ps = 0.f, pq = 0.f;
    #pragma unroll
    for (int r = 0; r < 4; ++r) {
        int node = row0 + quad * 4 + r;
        float v = acc[r] + bias;
        if (node < N_NODES) ybuf[(size_t)node * 64 + col] = v;
        else v = 0.f;
        ps += v; pq += v * v;
    }
    ps += __shfl_xor(ps, 16); pq += __shfl_xor(pq, 16);
    ps += __shfl_xor(ps, 32); pq += __shfl_xor(pq, 32);
    if (quad == 0) {
        float* st = stat_l + (blockIdx.x & (STAT_SHARDS - 1)) * 128;
        atomicAdd(&st[col], ps);
        atomicAdd(&st[64 + col], pq);
    }
}

// ---------------------------------------------------------------------------
// K6: out = sigmoid( fc2_w . lrelu(bn(y)) + fc2_b )
// ---------------------------------------------------------------------------
__global__ void k_final(const float* __restrict__ y, const float* __restrict__ stat_l,
                        const float* __restrict__ gw, const float* __restrict__ gb,
                        const float* __restrict__ w2, const float* __restrict__ b2,
                        float* __restrict__ out) {
    __shared__ float sc[64], sh[64], w[64];
    int t = threadIdx.x;
    if (t < 64) {
        float s0 = 0.f, q0 = 0.f;
        #pragma unroll
        for (int j = 0; j < STAT_SHARDS; ++j) {
            s0 += stat_l[j * 128 + t];
            q0 += stat_l[j * 128 + 64 + t];
        }
        float mmm = s0 * (1.0f / N_NODES);
        float var = q0 * (1.0f / N_NODES) - mmm * mmm;
        float s = gw[t] * rsqrtf(var + BN_EPS);
        sc[t] = s; sh[t] = gb[t] - mmm * s; w[t] = w2[t];
    }
    __syncthreads();
    int i = blockIdx.x * blockDim.x + t;
    if (i >= N_NODES) return;
    float z = b2[0];
    const float* row = y + (size_t)i * 64;
    #pragma unroll
    for (int c = 0; c < 64; c += 4) {
        float4 v4 = *(const float4*)(row + c);
        float v;
        v = v4.x * sc[c]   + sh[c];   v = v > 0.f ? v : SLOPE * v; z += v * w[c];
        v = v4.y * sc[c+1] + sh[c+1]; v = v > 0.f ? v : SLOPE * v; z += v * w[c+1];
        v = v4.z * sc[c+2] + sh[c+2]; v = v > 0.f ? v : SLOPE * v; z += v * w[c+2];
        v = v4.w * sc[c+3] + sh[c+3]; v = v > 0.f ? v : SLOPE * v; z += v * w[c+3];
    }
    out[i] = 1.f / (1.f + __expf(-z));
}

// ---------------------------------------------------------------------------
extern "C" void kernel_launch(void* const* d_in, const int* in_sizes, int n_in,
                              void* d_out, int out_size, void* d_ws, size_t ws_size,
                              hipStream_t stream) {
    const float* emb_deg = (const float*)d_in[0];
    const float* emb_lab = (const float*)d_in[1];
    const float* wA[3]  = {(const float*)d_in[2],  (const float*)d_in[8],  (const float*)d_in[14]};
    const float* bA[3]  = {(const float*)d_in[3],  (const float*)d_in[9],  (const float*)d_in[15]};
    const float* wB[3]  = {(const float*)d_in[4],  (const float*)d_in[10], (const float*)d_in[16]};
    const float* bB[3]  = {(const float*)d_in[5],  (const float*)d_in[11], (const float*)d_in[17]};
    const float* bnw[3] = {(const float*)d_in[6],  (const float*)d_in[12], (const float*)d_in[18]};
    const float* bnb[3] = {(const float*)d_in[7],  (const float*)d_in[13], (const float*)d_in[19]};
    const float* fc1_w  = (const float*)d_in[20];
    const float* fc1_b  = (const float*)d_in[21];
    const float* fcbn_w = (const float*)d_in[22];
    const float* fcbn_b = (const float*)d_in[23];
    const float* fc2_w  = (const float*)d_in[24];
    const float* fc2_b  = (const float*)d_in[25];
    const int* node_deg = (const int*)d_in[26];
    const int* node_lab = (const int*)d_in[27];
    const int* src = (const int*)d_in[28];
    const int* dst = src + E_EDGES;
    float* out = (float*)d_out;

    // workspace layout
    float* ws   = (float*)d_ws;
    float* ybf  = ws;                                  // N*64 fp32
    float* stat = ybf + (size_t)N_NODES * 64;          // 4 * 32 * 128 floats
    uint_t* x0u = (uint_t*)(stat + 4 * STAT_SHARDS * 128);  // N*64 uints
    uint_t* x1u = x0u + (size_t)N_NODES * 64;          // N*32
    uint_t* x2u = x1u + (size_t)N_NODES * 32;          // N*32
    int* epk    = (int*)(x2u + (size_t)N_NODES * 32);  // E packed edges
    int* rank   = epk + E_EDGES;                       // E
    ushort_t* wbf = (ushort_t*)(rank + E_EDGES);       // WTOT bf16
    ushort_t* Ptb = wbf + WTOT;                        // 128*96 bf16
    int* cdeg   = (int*)(Ptb + 128 * 96);              // N
    int* rowptr = cdeg + N_NODES;
    int* ncls   = rowptr + N_NODES;

    const int RB = (N_NODES + 15) / 16;            // 3125 row-tile blocks
    const int VB = (N_NODES * 16 + 255) / 256;     // 3125 float4 elementwise blocks
    const int NB = (N_NODES + 255) / 256;          // 196 node blocks
    const int FRONT = CVT_BLOCKS + P_BLOCKS + X0_BLOCKS + E_BLOCKS + STATZ_BLOCKS;

    hipMemsetAsync(cdeg, 0, (size_t)N_NODES * sizeof(int), stream);

    k_front<<<FRONT, 256, 0, stream>>>(wA[0], wB[0], wA[1], wB[1], wA[2], wB[2],
        fc1_w, wbf, emb_deg, emb_lab, Ptb, node_deg, node_lab, x0u, ncls,
        dst, cdeg, rank, stat);

    k_scan<<<SCAN_BLOCKS, 256, 0, stream>>>(cdeg, rowptr);
    k_fill<<<FILL_PASSES * E_BLOCKS, 256, 0, stream>>>(src, dst, ncls, rowptr,
                                                       rank, epk, E_BLOCKS);

    // ---- layer 0: LDS-histogram + dense MFMA
    k_mlp0<<<RB, 256, 0, stream>>>(rowptr, cdeg, epk, ncls, Ptb, bA[0],
                                   wbf + OWB0, bB[0], ybf, stat);
    k_bn_apply<<<VB, 256, 0, stream>>>(ybf, stat, bnw[0], bnb[0], x1u);

    // ---- layer 1
    k_mlp64<<<RB, 256, 0, stream>>>((const ushort_t*)x1u, rowptr, cdeg, epk,
        wbf + OWA1, bA[1], wbf + OWB1, bB[1], ybf, stat + STAT_SHARDS * 128);
    k_bn_apply<<<VB, 256, 0, stream>>>(ybf, stat + STAT_SHARDS * 128,
                                       bnw[1], bnb[1], x2u);

    // ---- layer 2 (BN fused into fc1)
    k_mlp64<<<RB, 256, 0, stream>>>((const ushort_t*)x2u, rowptr, cdeg, epk,
        wbf + OWA2, bA[2], wbf + OWB2, bB[2], ybf, stat + 2 * STAT_SHARDS * 128);

    float* stf = stat + 3 * STAT_SHARDS * 128;
    k_fc1<<<RB, 256, 0, stream>>>(x0u, x1u, x2u, ybf, stat + 2 * STAT_SHARDS * 128,
        bnw[2], bnb[2], wbf + OFC1, fc1_b, ybf, stf);
    k_final<<<NB, 256, 0, stream>>>(ybf, stf, fcbn_w, fcbn_b, fc2_w, fc2_b, out);
}

// Round 16
// 331.006 us; speedup vs baseline: 1.0426x; 1.0426x over previous
//
#include <hip/hip_runtime.h>

// Problem constants (fixed by reference)
#define N_NODES 50000
#define E_EDGES 800000
#define BN_EPS 1e-5f
#define SLOPE 0.01f

#define SCAN_CHUNK 2048
#define SCAN_BLOCKS ((N_NODES + SCAN_CHUNK - 1) / SCAN_CHUNK)   // 25
#define STAT_SHARDS 32
#define FILL_PASSES 8

typedef unsigned short ushort_t;
typedef unsigned int uint_t;
typedef short short8 __attribute__((ext_vector_type(8)));
typedef float floatx4 __attribute__((ext_vector_type(4)));

__device__ __forceinline__ float ulo(uint_t v) { return __uint_as_float(v << 16); }
__device__ __forceinline__ float uhi(uint_t v) { return __uint_as_float(v & 0xffff0000u); }
__device__ __forceinline__ ushort_t f2b(float f) {   // round-to-nearest-even
    uint_t u = __float_as_uint(f);
    return (ushort_t)((u + 0x7fffu + ((u >> 16) & 1u)) >> 16);
}
__device__ __forceinline__ uint_t pack2(float a, float b) {
    return (uint_t)f2b(a) | ((uint_t)f2b(b) << 16);
}

// bf16 weight buffer offsets (elements)
#define OWA0 0
#define OWB0 16384
#define OWA1 24576
#define OWB1 28672
#define OWA2 32768
#define OWB2 36864
#define OFC1 40960
#define WTOT 61440
#define CVT_BLOCKS ((WTOT + 255) / 256)       // 240
#define P_BLOCKS 48                           // 96*128/256
#define STATZ_BLOCKS 16                       // 16384 floats / (256*4)
#define E_BLOCKS ((E_EDGES + 255) / 256)      // 3125

// ---------------------------------------------------------------------------
// K-prep: [0,240) weight convert; [240,288) Pt; [288,304) zero stat buffer.
// No atomics, no scattered writes — safe to fuse these three.
// ---------------------------------------------------------------------------
__global__ void k_prep(const float* __restrict__ wa0, const float* __restrict__ wb0,
                       const float* __restrict__ wa1, const float* __restrict__ wb1,
                       const float* __restrict__ wa2, const float* __restrict__ wb2,
                       const float* __restrict__ fc1w, ushort_t* __restrict__ wdst,
                       const float* __restrict__ ed, const float* __restrict__ el,
                       ushort_t* __restrict__ Pt, float* __restrict__ stat) {
    int b = blockIdx.x, t = threadIdx.x;
    if (b < CVT_BLOCKS) {
        int i = b * 256 + t;
        if (i >= WTOT) return;
        float v;
        if      (i < OWB0) v = wa0[i];
        else if (i < OWA1) v = wb0[i - OWB0];
        else if (i < OWB1) v = wa1[i - OWA1];
        else if (i < OWA2) v = wb1[i - OWB1];
        else if (i < OWB2) v = wa2[i - OWA2];
        else if (i < OFC1) v = wb2[i - OWB2];
        else               v = fc1w[i - OFC1];
        wdst[i] = f2b(v);
    } else if (b < CVT_BLOCKS + P_BLOCKS) {
        int pid = (b - CVT_BLOCKS) * 256 + t;   // c*128 + j over 96*128
        int c = pid >> 7, j = pid & 127;
        float acc = 0.f;
        if (c < 64) {
            const float* dr = ed + c * 64;
            const float* wr = wa0 + (size_t)j * 128;
            #pragma unroll 8
            for (int k = 0; k < 64; ++k) acc += dr[k] * wr[k];
        } else if (c < 80) {
            const float* dr = el + (c - 64) * 64;
            const float* wr = wa0 + (size_t)j * 128 + 64;
            #pragma unroll 8
            for (int k = 0; k < 64; ++k) acc += dr[k] * wr[k];
        }
        Pt[(size_t)j * 96 + c] = f2b(acc);
    } else {
        int idx = (b - CVT_BLOCKS - P_BLOCKS) * 256 + t;
        if (idx < 4096)
            *(float4*)(stat + (size_t)idx * 4) = make_float4(0.f, 0.f, 0.f, 0.f);
    }
}

// ---------------------------------------------------------------------------
// K0: x0 (bf16) = concat(emb_deg[deg[n]], emb_lab[lab[n]]); ncls
// ---------------------------------------------------------------------------
__global__ void k_build_x0(const float* __restrict__ ed, const float* __restrict__ el,
                           const int* __restrict__ nd, const int* __restrict__ nl,
                           uint_t* __restrict__ x0u, int* __restrict__ ncls) {
    int idx = blockIdx.x * blockDim.x + threadIdx.x;  // N*64 uint slots
    if (idx >= N_NODES * 64) return;
    int n = idx >> 6, c = idx & 63;
    int d = nd[n], l = nl[n];
    if (c == 0) ncls[n] = d | (l << 16);
    float2 v = (c < 32) ? *(const float2*)(ed + d * 64 + c * 2)
                        : *(const float2*)(el + l * 64 + (c - 32) * 2);
    x0u[(size_t)n * 64 + c] = pack2(v.x, v.y);
}

// ---------------------------------------------------------------------------
// K-degrank: runs FIRST (exclusive L2 for cdeg — R15 showed mixing this with
// streaming writes thrashes the atomic working set's dirty lines).
// ---------------------------------------------------------------------------
__global__ void k_degrank(const int* __restrict__ dst, int* __restrict__ deg,
                          int* __restrict__ rank) {
    int e = blockIdx.x * blockDim.x + threadIdx.x;
    if (e >= E_EDGES) return;
    rank[e] = atomicAdd(&deg[dst[e]], 1);   // old count = slot within bucket
}

// ---------------------------------------------------------------------------
// K-scan: single-kernel exclusive scan. Block b sums deg[0..b*2048) itself.
// ---------------------------------------------------------------------------
__global__ __launch_bounds__(256) void k_scan(const int* __restrict__ deg,
                                              int* __restrict__ rowptr) {
    __shared__ int part[256];
    __shared__ int bofs_sh;
    int t = threadIdx.x, b = blockIdx.x;
    int pre = 0;
    int lim = b * SCAN_CHUNK;
    for (int i = t; i < lim; i += 256) pre += deg[i];
    part[t] = pre;
    __syncthreads();
    #pragma unroll
    for (int off = 128; off; off >>= 1) {
        if (t < off) part[t] += part[t + off];
        __syncthreads();
    }
    if (t == 0) bofs_sh = part[0];
    __syncthreads();
    int bofs = bofs_sh;
    __syncthreads();                    // part[] about to be reused
    int base = b * SCAN_CHUNK + t * 8;
    int vals[8];
    int s = 0;
    #pragma unroll
    for (int i = 0; i < 8; ++i) {
        int idx = base + i;
        vals[i] = (idx < N_NODES) ? deg[idx] : 0;
        s += vals[i];
    }
    part[t] = s;
    __syncthreads();
    #pragma unroll
    for (int off = 1; off < 256; off <<= 1) {
        int v = (t >= off) ? part[t - off] : 0;
        __syncthreads();
        part[t] += v;
        __syncthreads();
    }
    int run = bofs + part[t] - s;
    #pragma unroll
    for (int i = 0; i < 8; ++i) {
        int idx = base + i;
        if (idx < N_NODES) {
            rowptr[idx] = run;
            run += vals[i];
        }
    }
}

// k_fill: 8 dst-range passes; pass-p blocks adjacent in dispatch order so the
// write window stays L2-hot. No atomics (rank precomputed).
// epk record: src(16b) | deg(6b)<<16 | lab(4b)<<22
__global__ void k_fill(const int* __restrict__ src, const int* __restrict__ dst,
                       const int* __restrict__ ncls, const int* __restrict__ rowptr,
                       const int* __restrict__ rank, int* __restrict__ epk,
                       int blocks_per_pass) {
    int p = blockIdx.x / blocks_per_pass;
    int e = (blockIdx.x % blocks_per_pass) * blockDim.x + threadIdx.x;
    if (e >= E_EDGES) return;
    int d = dst[e];
    const int span = (N_NODES + FILL_PASSES - 1) / FILL_PASSES;   // 6250
    int lo = p * span;
    if (d < lo || d >= lo + span) return;
    int s = src[e];
    int c = ncls[s];
    epk[rowptr[d] + rank[e]] = s | ((c & 63) << 16) | ((c >> 16) << 22);
}

// ---------------------------------------------------------------------------
// K-mlp0: layer 0. LDS class histogram (1 lane/edge) + dense MFMA.
// ---------------------------------------------------------------------------
__global__ __launch_bounds__(256, 8) void k_mlp0(
        const int* __restrict__ rowptr, const int* __restrict__ cdeg,
        const int* __restrict__ epk, const int* __restrict__ ncls,
        const ushort_t* __restrict__ Pt, const float* __restrict__ ba,
        const ushort_t* __restrict__ wbB, const float* __restrict__ bb,
        float* __restrict__ ybuf, float* __restrict__ stat_l) {
    constexpr int LHS = 98;
    constexpr int LDC = 104;
    constexpr int LDH = 136;
    __shared__ int hist[16 * LHS];
    __shared__ ushort_t xs[16 * LDC];
    __shared__ ushort_t hs[16 * LDH];
    uint_t* xsu = (uint_t*)xs;
    int t = threadIdx.x;
    int row0 = blockIdx.x * 16;
    int lane = t & 63, wv = t >> 6;
    int half = lane >> 5, hl = lane & 31;

    for (int i = t; i < 16 * LHS; i += 256) hist[i] = 0;
    __syncthreads();

    for (int i = 0; i < 2; ++i) {
        int lr = wv * 4 + i * 2 + half, node = row0 + lr;
        if (node < N_NODES) {
            if (hl == 0) {
                int c = ncls[node];
                atomicAdd(&hist[lr * LHS + (c & 0xffff)], 1);
                atomicAdd(&hist[lr * LHS + 64 + (c >> 16)], 1);
            }
            int start = rowptr[node], n = cdeg[node];
            for (int j0 = 0; j0 < n; j0 += 32) {
                int m = n - j0; if (m > 32) m = 32;
                if (hl < m) {
                    int ev = epk[start + j0 + hl];
                    atomicAdd(&hist[lr * LHS + ((ev >> 16) & 63)], 1);
                    atomicAdd(&hist[lr * LHS + 64 + ((ev >> 22) & 15)], 1);
                }
            }
        }
    }
    __syncthreads();

    for (int i = t; i < 16 * 48; i += 256) {
        int row = i / 48, c2 = i % 48;
        uint_t v = 0;
        if (c2 < 40)
            v = pack2((float)hist[row * LHS + c2 * 2],
                      (float)hist[row * LHS + c2 * 2 + 1]);
        xsu[row * 52 + c2] = v;
    }
    __syncthreads();

    int m = lane & 15, quad = lane >> 4;

    // ---- lin1 (MFMA, K=96) + lrelu -> hs
    {
        floatx4 acc[2];
        acc[0] = (floatx4){0.f, 0.f, 0.f, 0.f};
        acc[1] = (floatx4){0.f, 0.f, 0.f, 0.f};
        #pragma unroll
        for (int ks = 0; ks < 3; ++ks) {
            short8 af = *(const short8*)(xs + m * LDC + ks * 32 + quad * 8);
            #pragma unroll
            for (int g = 0; g < 2; ++g) {
                int col = (wv * 2 + g) * 16 + m;
                short8 bf = *(const short8*)(Pt + (size_t)col * 96 + ks * 32 + quad * 8);
                acc[g] = __builtin_amdgcn_mfma_f32_16x16x32_bf16(af, bf, acc[g], 0, 0, 0);
            }
        }
        #pragma unroll
        for (int g = 0; g < 2; ++g) {
            int col = (wv * 2 + g) * 16 + m;
            float bias = ba[col];
            #pragma unroll
            for (int r = 0; r < 4; ++r) {
                float v = acc[g][r] + bias;
                v = v > 0.f ? v : SLOPE * v;
                hs[(quad * 4 + r) * LDH + col] = f2b(v);
            }
        }
    }
    __syncthreads();

    // ---- lin2 (MFMA, K=128)
    {
        floatx4 acc = (floatx4){0.f, 0.f, 0.f, 0.f};
        int col = wv * 16 + m;
        #pragma unroll
        for (int ks = 0; ks < 4; ++ks) {
            short8 af = *(const short8*)(hs + m * LDH + ks * 32 + quad * 8);
            short8 bf = *(const short8*)(wbB + (size_t)col * 128 + ks * 32 + quad * 8);
            acc = __builtin_amdgcn_mfma_f32_16x16x32_bf16(af, bf, acc, 0, 0, 0);
        }
        float bias = bb[col];
        float ps = 0.f, pq = 0.f;
        #pragma unroll
        for (int r = 0; r < 4; ++r) {
            int node = row0 + quad * 4 + r;
            float v = acc[r] + bias;
            if (node < N_NODES) ybuf[(size_t)node * 64 + col] = v;
            else v = 0.f;
            ps += v; pq += v * v;
        }
        ps += __shfl_xor(ps, 16); pq += __shfl_xor(pq, 16);
        ps += __shfl_xor(ps, 32); pq += __shfl_xor(pq, 32);
        if (quad == 0) {
            float* st = stat_l + (blockIdx.x & (STAT_SHARDS - 1)) * 128;
            atomicAdd(&st[col], ps);
            atomicAdd(&st[64 + col], pq);
        }
    }
}

// ---------------------------------------------------------------------------
// K2: layers 1,2 (D=64). Gather via uint4 row segments; remainder __shfl
// hoisted out of the predicate (R13 bug).
// ---------------------------------------------------------------------------
__global__ __launch_bounds__(256, 8) void k_mlp64(
        const ushort_t* __restrict__ xb,
        const int* __restrict__ rowptr, const int* __restrict__ cdeg,
        const int* __restrict__ epk,
        const ushort_t* __restrict__ waB, const float* __restrict__ ba,
        const ushort_t* __restrict__ wbB, const float* __restrict__ bb,
        float* __restrict__ ybuf, float* __restrict__ stat_l) {
    constexpr int LDWB = 72;   // ushorts; row stride 144B (16B multiple)
    __shared__ ushort_t xs[16 * LDWB];
    __shared__ ushort_t hs[16 * LDWB];
    int t = threadIdx.x;
    int row0 = blockIdx.x * 16;
    int lane = t & 63, wv = t >> 6;
    int half = lane >> 5, hl = lane & 31;
    int g = hl >> 3, sseg = hl & 7;           // edge-group, 16B row segment
    const uint4* xu4 = (const uint4*)xb;      // row = 8 uint4

    for (int i = 0; i < 2; ++i) {
        int lr = wv * 4 + i * 2 + half, node = row0 + lr;
        float acc[8] = {0.f, 0.f, 0.f, 0.f, 0.f, 0.f, 0.f, 0.f};
        if (node < N_NODES) {
            int start = rowptr[node], n = cdeg[node];
            if (g == 0) {   // self row (group 0 lanes)
                uint4 v = xu4[(size_t)node * 8 + sseg];
                acc[0] += ulo(v.x); acc[1] += uhi(v.x);
                acc[2] += ulo(v.y); acc[3] += uhi(v.y);
                acc[4] += ulo(v.z); acc[5] += uhi(v.z);
                acc[6] += ulo(v.w); acc[7] += uhi(v.w);
            }
            for (int j0 = 0; j0 < n; j0 += 32) {
                int m = n - j0; if (m > 32) m = 32;
                int ev = (hl < m) ? epk[start + j0 + hl] : 0;
                int j = 0;
                for (; j + 8 <= m; j += 8) {
                    int sa = __shfl(ev, j + g, 32) & 0xffff;
                    int sb = __shfl(ev, j + 4 + g, 32) & 0xffff;
                    uint4 va = xu4[(size_t)sa * 8 + sseg];
                    uint4 vb = xu4[(size_t)sb * 8 + sseg];
                    acc[0] += ulo(va.x); acc[1] += uhi(va.x);
                    acc[2] += ulo(va.y); acc[3] += uhi(va.y);
                    acc[4] += ulo(va.z); acc[5] += uhi(va.z);
                    acc[6] += ulo(va.w); acc[7] += uhi(va.w);
                    acc[0] += ulo(vb.x); acc[1] += uhi(vb.x);
                    acc[2] += ulo(vb.y); acc[3] += uhi(vb.y);
                    acc[4] += ulo(vb.z); acc[5] += uhi(vb.z);
                    acc[6] += ulo(vb.w); acc[7] += uhi(vb.w);
                }
                for (; j < m; j += 4) {
                    int sa = __shfl(ev, j + g, 32) & 0xffff;  // all lanes exec
                    if (g < m - j) {
                        uint4 va = xu4[(size_t)sa * 8 + sseg];
                        acc[0] += ulo(va.x); acc[1] += uhi(va.x);
                        acc[2] += ulo(va.y); acc[3] += uhi(va.y);
                        acc[4] += ulo(va.z); acc[5] += uhi(va.z);
                        acc[6] += ulo(va.w); acc[7] += uhi(va.w);
                    }
                }
            }
        }
        #pragma unroll
        for (int q = 0; q < 8; ++q) {
            acc[q] += __shfl_xor(acc[q], 8, 32);
            acc[q] += __shfl_xor(acc[q], 16, 32);
        }
        if (g == 0) {
            uint4 pv = make_uint4(pack2(acc[0], acc[1]), pack2(acc[2], acc[3]),
                                  pack2(acc[4], acc[5]), pack2(acc[6], acc[7]));
            *(uint4*)(xs + lr * LDWB + sseg * 8) = pv;
        }
    }
    __syncthreads();

    int m = lane & 15, quad = lane >> 4;

    // ---- lin1 (MFMA) + lrelu -> hs
    {
        floatx4 acc = (floatx4){0.f, 0.f, 0.f, 0.f};
        int col = wv * 16 + m;
        #pragma unroll
        for (int ks = 0; ks < 2; ++ks) {
            short8 af = *(const short8*)(xs + m * LDWB + ks * 32 + quad * 8);
            short8 bf = *(const short8*)(waB + (size_t)col * 64 + ks * 32 + quad * 8);
            acc = __builtin_amdgcn_mfma_f32_16x16x32_bf16(af, bf, acc, 0, 0, 0);
        }
        float bias = ba[col];
        #pragma unroll
        for (int r = 0; r < 4; ++r) {
            float v = acc[r] + bias;
            v = v > 0.f ? v : SLOPE * v;
            hs[(quad * 4 + r) * LDWB + col] = f2b(v);
        }
    }
    __syncthreads();

    // ---- lin2 (MFMA)
    {
        floatx4 acc = (floatx4){0.f, 0.f, 0.f, 0.f};
        int col = wv * 16 + m;
        #pragma unroll
        for (int ks = 0; ks < 2; ++ks) {
            short8 af = *(const short8*)(hs + m * LDWB + ks * 32 + quad * 8);
            short8 bf = *(const short8*)(wbB + (size_t)col * 64 + ks * 32 + quad * 8);
            acc = __builtin_amdgcn_mfma_f32_16x16x32_bf16(af, bf, acc, 0, 0, 0);
        }
        float bias = bb[col];
        float ps = 0.f, pq = 0.f;
        #pragma unroll
        for (int r = 0; r < 4; ++r) {
            int node = row0 + quad * 4 + r;
            float v = acc[r] + bias;
            if (node < N_NODES) ybuf[(size_t)node * 64 + col] = v;
            else v = 0.f;
            ps += v; pq += v * v;
        }
        ps += __shfl_xor(ps, 16); pq += __shfl_xor(pq, 16);
        ps += __shfl_xor(ps, 32); pq += __shfl_xor(pq, 32);
        if (quad == 0) {
            float* st = stat_l + (blockIdx.x & (STAT_SHARDS - 1)) * 128;
            atomicAdd(&st[col], ps);
            atomicAdd(&st[64 + col], pq);
        }
    }
}

// ---------------------------------------------------------------------------
// K4: x_out(bf16) = lrelu(y*scale + shift); stats summed over shards
// ---------------------------------------------------------------------------
__global__ void k_bn_apply(const float* __restrict__ y, const float* __restrict__ stat_l,
                           const float* __restrict__ gw, const float* __restrict__ gb,
                           uint_t* __restrict__ xo) {
    __shared__ float sc[64], sh[64];
    int t = threadIdx.x;
    if (t < 64) {
        float s0 = 0.f, q0 = 0.f;
        #pragma unroll
        for (int j = 0; j < STAT_SHARDS; ++j) {
            s0 += stat_l[j * 128 + t];
            q0 += stat_l[j * 128 + 64 + t];
        }
        float mmm = s0 * (1.0f / N_NODES);
        float var = q0 * (1.0f / N_NODES) - mmm * mmm;
        float s = gw[t] * rsqrtf(var + BN_EPS);
        sc[t] = s; sh[t] = gb[t] - mmm * s;
    }
    __syncthreads();
    int idx = blockIdx.x * blockDim.x + t;    // N*16 float4 slots
    if (idx >= N_NODES * 16) return;
    int c4 = (idx & 15) * 4;
    float4 v4 = *(const float4*)(y + (size_t)idx * 4);
    float o0 = v4.x * sc[c4]     + sh[c4];     o0 = o0 > 0.f ? o0 : SLOPE * o0;
    float o1 = v4.y * sc[c4 + 1] + sh[c4 + 1]; o1 = o1 > 0.f ? o1 : SLOPE * o1;
    float o2 = v4.z * sc[c4 + 2] + sh[c4 + 2]; o2 = o2 > 0.f ? o2 : SLOPE * o2;
    float o3 = v4.w * sc[c4 + 3] + sh[c4 + 3]; o3 = o3 > 0.f ? o3 : SLOPE * o3;
    xo[(size_t)idx * 2]     = pack2(o0, o1);
    xo[(size_t)idx * 2 + 1] = pack2(o2, o3);
}

// ---------------------------------------------------------------------------
// K5: fc1 (MFMA), K=320. x3 segment computed INLINE from ybuf (layer-2 pre-BN)
// + stat2 — no third bn_apply. Block touches only its own 16 ybuf rows.
// ---------------------------------------------------------------------------
__global__ __launch_bounds__(256, 8) void k_fc1(
        const uint_t* __restrict__ x0u, const uint_t* __restrict__ x1u,
        const uint_t* __restrict__ x2u, const float* __restrict__ ybuf_in,
        const float* __restrict__ stat2,
        const float* __restrict__ gw2, const float* __restrict__ gb2,
        const ushort_t* __restrict__ wB, const float* __restrict__ b,
        float* __restrict__ ybuf, float* __restrict__ stat_l) {
    constexpr int LDWB = 328;            // ushort stride (320+8), /2=164 uints
    __shared__ ushort_t xs[16 * LDWB];
    __shared__ float sc2[64], sh2[64];
    uint_t* xsu = (uint_t*)xs;
    int t = threadIdx.x;
    int row0 = blockIdx.x * 16;

    if (t < 64) {   // layer-2 BN coefficients from sharded stats
        float s0 = 0.f, q0 = 0.f;
        #pragma unroll
        for (int j = 0; j < STAT_SHARDS; ++j) {
            s0 += stat2[j * 128 + t];
            q0 += stat2[j * 128 + 64 + t];
        }
        float mmm = s0 * (1.0f / N_NODES);
        float var = q0 * (1.0f / N_NODES) - mmm * mmm;
        float s = gw2[t] * rsqrtf(var + BN_EPS);
        sc2[t] = s; sh2[t] = gb2[t] - mmm * s;
    }
    __syncthreads();

    for (int i = t; i < 16 * 160; i += 256) {
        int row = i / 160, c = i % 160;
        int g = row0 + row;
        uint_t v = 0;
        if (g < N_NODES) {
            if      (c < 64)  v = x0u[(size_t)g * 64 + c];
            else if (c < 96)  v = x1u[(size_t)g * 32 + (c - 64)];
            else if (c < 128) v = x2u[(size_t)g * 32 + (c - 96)];
            else {
                int cc = (c - 128) * 2;
                float2 yv = *(const float2*)(ybuf_in + (size_t)g * 64 + cc);
                float o0 = yv.x * sc2[cc]     + sh2[cc];
                float o1 = yv.y * sc2[cc + 1] + sh2[cc + 1];
                o0 = o0 > 0.f ? o0 : SLOPE * o0;
                o1 = o1 > 0.f ? o1 : SLOPE * o1;
                v = pack2(o0, o1);
            }
        }
        xsu[row * 164 + c] = v;
    }
    __syncthreads();

    int lane = t & 63, wv = t >> 6;
    int m = lane & 15, quad = lane >> 4;
    int col = wv * 16 + m;
    floatx4 acc = (floatx4){0.f, 0.f, 0.f, 0.f};
    #pragma unroll
    for (int ks = 0; ks < 10; ++ks) {
        short8 af = *(const short8*)(xs + m * LDWB + ks * 32 + quad * 8);
        short8 bf = *(const short8*)(wB + (size_t)col * 320 + ks * 32 + quad * 8);
        acc = __builtin_amdgcn_mfma_f32_16x16x32_bf16(af, bf, acc, 0, 0, 0);
    }
    float bias = b[col];
    float ps = 0.f, pq = 0.f;
    #pragma unroll
    for (int r = 0; r < 4; ++r) {
        int node = row0 + quad * 4 + r;
        float v = acc[r] + bias;
        if (node < N_NODES) ybuf[(size_t)node * 64 + col] = v;
        else v = 0.f;
        ps += v; pq += v * v;
    }
    ps += __shfl_xor(ps, 16); pq += __shfl_xor(pq, 16);
    ps += __shfl_xor(ps, 32); pq += __shfl_xor(pq, 32);
    if (quad == 0) {
        float* st = stat_l + (blockIdx.x & (STAT_SHARDS - 1)) * 128;
        atomicAdd(&st[col], ps);
        atomicAdd(&st[64 + col], pq);
    }
}

// ---------------------------------------------------------------------------
// K6: out = sigmoid( fc2_w . lrelu(bn(y)) + fc2_b )
// ---------------------------------------------------------------------------
__global__ void k_final(const float* __restrict__ y, const float* __restrict__ stat_l,
                        const float* __restrict__ gw, const float* __restrict__ gb,
                        const float* __restrict__ w2, const float* __restrict__ b2,
                        float* __restrict__ out) {
    __shared__ float sc[64], sh[64], w[64];
    int t = threadIdx.x;
    if (t < 64) {
        float s0 = 0.f, q0 = 0.f;
        #pragma unroll
        for (int j = 0; j < STAT_SHARDS; ++j) {
            s0 += stat_l[j * 128 + t];
            q0 += stat_l[j * 128 + 64 + t];
        }
        float mmm = s0 * (1.0f / N_NODES);
        float var = q0 * (1.0f / N_NODES) - mmm * mmm;
        float s = gw[t] * rsqrtf(var + BN_EPS);
        sc[t] = s; sh[t] = gb[t] - mmm * s; w[t] = w2[t];
    }
    __syncthreads();
    int i = blockIdx.x * blockDim.x + t;
    if (i >= N_NODES) return;
    float z = b2[0];
    const float* row = y + (size_t)i * 64;
    #pragma unroll
    for (int c = 0; c < 64; c += 4) {
        float4 v4 = *(const float4*)(row + c);
        float v;
        v = v4.x * sc[c]   + sh[c];   v = v > 0.f ? v : SLOPE * v; z += v * w[c];
        v = v4.y * sc[c+1] + sh[c+1]; v = v > 0.f ? v : SLOPE * v; z += v * w[c+1];
        v = v4.z * sc[c+2] + sh[c+2]; v = v > 0.f ? v : SLOPE * v; z += v * w[c+2];
        v = v4.w * sc[c+3] + sh[c+3]; v = v > 0.f ? v : SLOPE * v; z += v * w[c+3];
    }
    out[i] = 1.f / (1.f + __expf(-z));
}

// ---------------------------------------------------------------------------
extern "C" void kernel_launch(void* const* d_in, const int* in_sizes, int n_in,
                              void* d_out, int out_size, void* d_ws, size_t ws_size,
                              hipStream_t stream) {
    const float* emb_deg = (const float*)d_in[0];
    const float* emb_lab = (const float*)d_in[1];
    const float* wA[3]  = {(const float*)d_in[2],  (const float*)d_in[8],  (const float*)d_in[14]};
    const float* bA[3]  = {(const float*)d_in[3],  (const float*)d_in[9],  (const float*)d_in[15]};
    const float* wB[3]  = {(const float*)d_in[4],  (const float*)d_in[10], (const float*)d_in[16]};
    const float* bB[3]  = {(const float*)d_in[5],  (const float*)d_in[11], (const float*)d_in[17]};
    const float* bnw[3] = {(const float*)d_in[6],  (const float*)d_in[12], (const float*)d_in[18]};
    const float* bnb[3] = {(const float*)d_in[7],  (const float*)d_in[13], (const float*)d_in[19]};
    const float* fc1_w  = (const float*)d_in[20];
    const float* fc1_b  = (const float*)d_in[21];
    const float* fcbn_w = (const float*)d_in[22];
    const float* fcbn_b = (const float*)d_in[23];
    const float* fc2_w  = (const float*)d_in[24];
    const float* fc2_b  = (const float*)d_in[25];
    const int* node_deg = (const int*)d_in[26];
    const int* node_lab = (const int*)d_in[27];
    const int* src = (const int*)d_in[28];
    const int* dst = src + E_EDGES;
    float* out = (float*)d_out;

    // workspace layout
    float* ws   = (float*)d_ws;
    float* ybf  = ws;                                  // N*64 fp32
    float* stat = ybf + (size_t)N_NODES * 64;          // 4 * 32 * 128 floats
    uint_t* x0u = (uint_t*)(stat + 4 * STAT_SHARDS * 128);  // N*64 uints
    uint_t* x1u = x0u + (size_t)N_NODES * 64;          // N*32
    uint_t* x2u = x1u + (size_t)N_NODES * 32;          // N*32
    int* epk    = (int*)(x2u + (size_t)N_NODES * 32);  // E packed edges
    int* rank   = epk + E_EDGES;                       // E
    ushort_t* wbf = (ushort_t*)(rank + E_EDGES);       // WTOT bf16
    ushort_t* Ptb = wbf + WTOT;                        // 128*96 bf16
    int* cdeg   = (int*)(Ptb + 128 * 96);              // N
    int* rowptr = cdeg + N_NODES;
    int* ncls   = rowptr + N_NODES;

    const int RB = (N_NODES + 15) / 16;            // 3125 row-tile blocks
    const int VB = (N_NODES * 16 + 255) / 256;     // 3125 float4 elementwise blocks
    const int HB = (N_NODES * 64 + 255) / 256;     // 12500 build-x0 blocks
    const int NB = (N_NODES + 255) / 256;          // 196 node blocks

    hipMemsetAsync(cdeg, 0, (size_t)N_NODES * sizeof(int), stream);

    // degrank FIRST: exclusive L2 ownership of cdeg during the atomic storm
    k_degrank<<<E_BLOCKS, 256, 0, stream>>>(dst, cdeg, rank);
    k_prep<<<CVT_BLOCKS + P_BLOCKS + STATZ_BLOCKS, 256, 0, stream>>>(
        wA[0], wB[0], wA[1], wB[1], wA[2], wB[2], fc1_w, wbf,
        emb_deg, emb_lab, Ptb, stat);
    k_build_x0<<<HB, 256, 0, stream>>>(emb_deg, emb_lab, node_deg, node_lab, x0u, ncls);

    k_scan<<<SCAN_BLOCKS, 256, 0, stream>>>(cdeg, rowptr);
    k_fill<<<FILL_PASSES * E_BLOCKS, 256, 0, stream>>>(src, dst, ncls, rowptr,
                                                       rank, epk, E_BLOCKS);

    // ---- layer 0: LDS-histogram + dense MFMA
    k_mlp0<<<RB, 256, 0, stream>>>(rowptr, cdeg, epk, ncls, Ptb, bA[0],
                                   wbf + OWB0, bB[0], ybf, stat);
    k_bn_apply<<<VB, 256, 0, stream>>>(ybf, stat, bnw[0], bnb[0], x1u);

    // ---- layer 1
    k_mlp64<<<RB, 256, 0, stream>>>((const ushort_t*)x1u, rowptr, cdeg, epk,
        wbf + OWA1, bA[1], wbf + OWB1, bB[1], ybf, stat + STAT_SHARDS * 128);
    k_bn_apply<<<VB, 256, 0, stream>>>(ybf, stat + STAT_SHARDS * 128,
                                       bnw[1], bnb[1], x2u);

    // ---- layer 2 (BN fused into fc1)
    k_mlp64<<<RB, 256, 0, stream>>>((const ushort_t*)x2u, rowptr, cdeg, epk,
        wbf + OWA2, bA[2], wbf + OWB2, bB[2], ybf, stat + 2 * STAT_SHARDS * 128);

    float* stf = stat + 3 * STAT_SHARDS * 128;
    k_fc1<<<RB, 256, 0, stream>>>(x0u, x1u, x2u, ybf, stat + 2 * STAT_SHARDS * 128,
        bnw[2], bnb[2], wbf + OFC1, fc1_b, ybf, stf);
    k_final<<<NB, 256, 0, stream>>>(ybf, stf, fcbn_w, fcbn_b, fc2_w, fc2_b, out);
}

// Round 17
// 314.468 us; speedup vs baseline: 1.0975x; 1.0526x over previous
//
#include <hip/hip_runtime.h>

// Problem constants (fixed by reference)
#define N_NODES 50000
#define E_EDGES 800000
#define BN_EPS 1e-5f
#define SLOPE 0.01f

#define SCAN_CHUNK 2048
#define SCAN_BLOCKS ((N_NODES + SCAN_CHUNK - 1) / SCAN_CHUNK)   // 25
#define STAT_SHARDS 32
#define FILL_PASSES 8

typedef unsigned short ushort_t;
typedef unsigned int uint_t;
typedef short short8 __attribute__((ext_vector_type(8)));
typedef float floatx4 __attribute__((ext_vector_type(4)));

__device__ __forceinline__ float ulo(uint_t v) { return __uint_as_float(v << 16); }
__device__ __forceinline__ float uhi(uint_t v) { return __uint_as_float(v & 0xffff0000u); }
__device__ __forceinline__ ushort_t f2b(float f) {   // round-to-nearest-even
    uint_t u = __float_as_uint(f);
    return (ushort_t)((u + 0x7fffu + ((u >> 16) & 1u)) >> 16);
}
__device__ __forceinline__ uint_t pack2(float a, float b) {
    return (uint_t)f2b(a) | ((uint_t)f2b(b) << 16);
}

// bf16 weight buffer offsets (elements)
#define OWA0 0
#define OWB0 16384
#define OWA1 24576
#define OWB1 28672
#define OWA2 32768
#define OWB2 36864
#define OFC1 40960
#define WTOT 61440
#define CVT_BLOCKS ((WTOT + 255) / 256)       // 240
#define P_BLOCKS 48                           // 96*128/256
#define E_BLOCKS ((E_EDGES + 255) / 256)      // 3125

// ---------------------------------------------------------------------------
// K-prep: [0,240) weight fp32->bf16; [240,288) Pt[128,96]: Pt[j,c]=dot(dict_c,
// wa0_j), c>=80 -> 0 (K-pad).
// ---------------------------------------------------------------------------
__global__ void k_prep(const float* __restrict__ wa0, const float* __restrict__ wb0,
                       const float* __restrict__ wa1, const float* __restrict__ wb1,
                       const float* __restrict__ wa2, const float* __restrict__ wb2,
                       const float* __restrict__ fc1w, ushort_t* __restrict__ wdst,
                       const float* __restrict__ ed, const float* __restrict__ el,
                       ushort_t* __restrict__ Pt) {
    int b = blockIdx.x, t = threadIdx.x;
    if (b < CVT_BLOCKS) {
        int i = b * 256 + t;
        if (i >= WTOT) return;
        float v;
        if      (i < OWB0) v = wa0[i];
        else if (i < OWA1) v = wb0[i - OWB0];
        else if (i < OWB1) v = wa1[i - OWA1];
        else if (i < OWA2) v = wb1[i - OWB1];
        else if (i < OWB2) v = wa2[i - OWA2];
        else if (i < OFC1) v = wb2[i - OWB2];
        else               v = fc1w[i - OFC1];
        wdst[i] = f2b(v);
    } else {
        int pid = (b - CVT_BLOCKS) * 256 + t;   // c*128 + j over 96*128
        int c = pid >> 7, j = pid & 127;
        float acc = 0.f;
        if (c < 64) {
            const float* dr = ed + c * 64;
            const float* wr = wa0 + (size_t)j * 128;
            #pragma unroll 8
            for (int k = 0; k < 64; ++k) acc += dr[k] * wr[k];
        } else if (c < 80) {
            const float* dr = el + (c - 64) * 64;
            const float* wr = wa0 + (size_t)j * 128 + 64;
            #pragma unroll 8
            for (int k = 0; k < 64; ++k) acc += dr[k] * wr[k];
        }
        Pt[(size_t)j * 96 + c] = f2b(acc);
    }
}

// ---------------------------------------------------------------------------
// K0: x0 (bf16) = concat(emb_deg[deg[n]], emb_lab[lab[n]]); ncls
// ---------------------------------------------------------------------------
__global__ void k_build_x0(const float* __restrict__ ed, const float* __restrict__ el,
                           const int* __restrict__ nd, const int* __restrict__ nl,
                           uint_t* __restrict__ x0u, int* __restrict__ ncls) {
    int idx = blockIdx.x * blockDim.x + threadIdx.x;  // N*64 uint slots
    if (idx >= N_NODES * 64) return;
    int n = idx >> 6, c = idx & 63;
    int d = nd[n], l = nl[n];
    if (c == 0) ncls[n] = d | (l << 16);
    float2 v = (c < 32) ? *(const float2*)(ed + d * 64 + c * 2)
                        : *(const float2*)(el + l * 64 + (c - 32) * 2);
    x0u[(size_t)n * 64 + c] = pack2(v.x, v.y);
}

// ---------------------------------------------------------------------------
// CSR build: degree+rank -> scan (2-phase) -> range-partitioned fill
// ---------------------------------------------------------------------------
__global__ void k_degrank(const int* __restrict__ dst, int* __restrict__ deg,
                          int* __restrict__ rank) {
    int e = blockIdx.x * blockDim.x + threadIdx.x;
    if (e >= E_EDGES) return;
    rank[e] = atomicAdd(&deg[dst[e]], 1);   // old count = slot within bucket
}

__global__ __launch_bounds__(256) void k_scan_a(const int* __restrict__ deg,
                                                int* __restrict__ bsum) {
    __shared__ int wsum[4];
    int t = threadIdx.x, b = blockIdx.x;
    int base = b * SCAN_CHUNK + t * 8;
    int s = 0;
    #pragma unroll
    for (int i = 0; i < 8; ++i) {
        int idx = base + i;
        if (idx < N_NODES) s += deg[idx];
    }
    #pragma unroll
    for (int o = 32; o; o >>= 1) s += __shfl_down(s, o);
    if ((t & 63) == 0) wsum[t >> 6] = s;
    __syncthreads();
    if (t == 0) bsum[b] = wsum[0] + wsum[1] + wsum[2] + wsum[3];
}

// scan_c with inlined cross-block offset (sums <=25 bsum entries per block)
__global__ __launch_bounds__(256) void k_scan_c(const int* __restrict__ deg,
        const int* __restrict__ bsum, int* __restrict__ rowptr) {
    __shared__ int part[256];
    __shared__ int blockofs;
    int t = threadIdx.x, b = blockIdx.x;
    if (t < 64) {
        int v = (t < b) ? bsum[t] : 0;   // b <= 24 < 64
        #pragma unroll
        for (int o = 32; o; o >>= 1) v += __shfl_down(v, o);
        if (t == 0) blockofs = v;
    }
    int base = b * SCAN_CHUNK + t * 8;
    int vals[8];
    int s = 0;
    #pragma unroll
    for (int i = 0; i < 8; ++i) {
        int idx = base + i;
        vals[i] = (idx < N_NODES) ? deg[idx] : 0;
        s += vals[i];
    }
    part[t] = s;
    __syncthreads();
    #pragma unroll
    for (int off = 1; off < 256; off <<= 1) {
        int v = (t >= off) ? part[t - off] : 0;
        __syncthreads();
        part[t] += v;
        __syncthreads();
    }
    int run = blockofs + part[t] - s;
    #pragma unroll
    for (int i = 0; i < 8; ++i) {
        int idx = base + i;
        if (idx < N_NODES) {
            rowptr[idx] = run;
            run += vals[i];
        }
    }
}

// k_fill: 8 dst-range passes; pass-p blocks adjacent in dispatch order so the
// write window stays L2-hot. No atomics (rank precomputed).
// epk record: src(16b) | deg(6b)<<16 | lab(4b)<<22
__global__ void k_fill(const int* __restrict__ src, const int* __restrict__ dst,
                       const int* __restrict__ ncls, const int* __restrict__ rowptr,
                       const int* __restrict__ rank, int* __restrict__ epk,
                       int blocks_per_pass) {
    int p = blockIdx.x / blocks_per_pass;
    int e = (blockIdx.x % blocks_per_pass) * blockDim.x + threadIdx.x;
    if (e >= E_EDGES) return;
    int d = dst[e];
    const int span = (N_NODES + FILL_PASSES - 1) / FILL_PASSES;   // 6250
    int lo = p * span;
    if (d < lo || d >= lo + span) return;
    int s = src[e];
    int c = ncls[s];
    epk[rowptr[d] + rank[e]] = s | ((c & 63) << 16) | ((c >> 16) << 22);
}

// ---------------------------------------------------------------------------
// K-mlp0: layer 0. LDS class histogram (1 lane/edge) + dense MFMA.
// ---------------------------------------------------------------------------
__global__ __launch_bounds__(256, 8) void k_mlp0(
        const int* __restrict__ rowptr, const int* __restrict__ cdeg,
        const int* __restrict__ epk, const int* __restrict__ ncls,
        const ushort_t* __restrict__ Pt, const float* __restrict__ ba,
        const ushort_t* __restrict__ wbB, const float* __restrict__ bb,
        float* __restrict__ ybuf, float* __restrict__ stat_l) {
    constexpr int LHS = 98;
    constexpr int LDC = 104;
    constexpr int LDH = 136;
    __shared__ int hist[16 * LHS];
    __shared__ ushort_t xs[16 * LDC];
    __shared__ ushort_t hs[16 * LDH];
    uint_t* xsu = (uint_t*)xs;
    int t = threadIdx.x;
    int row0 = blockIdx.x * 16;
    int lane = t & 63, wv = t >> 6;
    int half = lane >> 5, hl = lane & 31;

    for (int i = t; i < 16 * LHS; i += 256) hist[i] = 0;
    __syncthreads();

    for (int i = 0; i < 2; ++i) {
        int lr = wv * 4 + i * 2 + half, node = row0 + lr;
        if (node < N_NODES) {
            if (hl == 0) {
                int c = ncls[node];
                atomicAdd(&hist[lr * LHS + (c & 0xffff)], 1);
                atomicAdd(&hist[lr * LHS + 64 + (c >> 16)], 1);
            }
            int start = rowptr[node], n = cdeg[node];
            for (int j0 = 0; j0 < n; j0 += 32) {
                int m = n - j0; if (m > 32) m = 32;
                if (hl < m) {
                    int ev = epk[start + j0 + hl];
                    atomicAdd(&hist[lr * LHS + ((ev >> 16) & 63)], 1);
                    atomicAdd(&hist[lr * LHS + 64 + ((ev >> 22) & 15)], 1);
                }
            }
        }
    }
    __syncthreads();

    for (int i = t; i < 16 * 48; i += 256) {
        int row = i / 48, c2 = i % 48;
        uint_t v = 0;
        if (c2 < 40)
            v = pack2((float)hist[row * LHS + c2 * 2],
                      (float)hist[row * LHS + c2 * 2 + 1]);
        xsu[row * 52 + c2] = v;
    }
    __syncthreads();

    int m = lane & 15, quad = lane >> 4;

    // ---- lin1 (MFMA, K=96) + lrelu -> hs
    {
        floatx4 acc[2];
        acc[0] = (floatx4){0.f, 0.f, 0.f, 0.f};
        acc[1] = (floatx4){0.f, 0.f, 0.f, 0.f};
        #pragma unroll
        for (int ks = 0; ks < 3; ++ks) {
            short8 af = *(const short8*)(xs + m * LDC + ks * 32 + quad * 8);
            #pragma unroll
            for (int g = 0; g < 2; ++g) {
                int col = (wv * 2 + g) * 16 + m;
                short8 bf = *(const short8*)(Pt + (size_t)col * 96 + ks * 32 + quad * 8);
                acc[g] = __builtin_amdgcn_mfma_f32_16x16x32_bf16(af, bf, acc[g], 0, 0, 0);
            }
        }
        #pragma unroll
        for (int g = 0; g < 2; ++g) {
            int col = (wv * 2 + g) * 16 + m;
            float bias = ba[col];
            #pragma unroll
            for (int r = 0; r < 4; ++r) {
                float v = acc[g][r] + bias;
                v = v > 0.f ? v : SLOPE * v;
                hs[(quad * 4 + r) * LDH + col] = f2b(v);
            }
        }
    }
    __syncthreads();

    // ---- lin2 (MFMA, K=128)
    {
        floatx4 acc = (floatx4){0.f, 0.f, 0.f, 0.f};
        int col = wv * 16 + m;
        #pragma unroll
        for (int ks = 0; ks < 4; ++ks) {
            short8 af = *(const short8*)(hs + m * LDH + ks * 32 + quad * 8);
            short8 bf = *(const short8*)(wbB + (size_t)col * 128 + ks * 32 + quad * 8);
            acc = __builtin_amdgcn_mfma_f32_16x16x32_bf16(af, bf, acc, 0, 0, 0);
        }
        float bias = bb[col];
        float ps = 0.f, pq = 0.f;
        #pragma unroll
        for (int r = 0; r < 4; ++r) {
            int node = row0 + quad * 4 + r;
            float v = acc[r] + bias;
            if (node < N_NODES) ybuf[(size_t)node * 64 + col] = v;
            else v = 0.f;
            ps += v; pq += v * v;
        }
        ps += __shfl_xor(ps, 16); pq += __shfl_xor(pq, 16);
        ps += __shfl_xor(ps, 32); pq += __shfl_xor(pq, 32);
        if (quad == 0) {
            float* st = stat_l + (blockIdx.x & (STAT_SHARDS - 1)) * 128;
            atomicAdd(&st[col], ps);
            atomicAdd(&st[64 + col], pq);
        }
    }
}

// ---------------------------------------------------------------------------
// K2: layers 1,2 (D=64). Gather via uint4 row segments; remainder __shfl
// hoisted out of the predicate (R13 bug).
// ---------------------------------------------------------------------------
__global__ __launch_bounds__(256, 8) void k_mlp64(
        const ushort_t* __restrict__ xb,
        const int* __restrict__ rowptr, const int* __restrict__ cdeg,
        const int* __restrict__ epk,
        const ushort_t* __restrict__ waB, const float* __restrict__ ba,
        const ushort_t* __restrict__ wbB, const float* __restrict__ bb,
        float* __restrict__ ybuf, float* __restrict__ stat_l) {
    constexpr int LDWB = 72;   // ushorts; row stride 144B (16B multiple)
    __shared__ ushort_t xs[16 * LDWB];
    __shared__ ushort_t hs[16 * LDWB];
    int t = threadIdx.x;
    int row0 = blockIdx.x * 16;
    int lane = t & 63, wv = t >> 6;
    int half = lane >> 5, hl = lane & 31;
    int g = hl >> 3, sseg = hl & 7;           // edge-group, 16B row segment
    const uint4* xu4 = (const uint4*)xb;      // row = 8 uint4

    for (int i = 0; i < 2; ++i) {
        int lr = wv * 4 + i * 2 + half, node = row0 + lr;
        float acc[8] = {0.f, 0.f, 0.f, 0.f, 0.f, 0.f, 0.f, 0.f};
        if (node < N_NODES) {
            int start = rowptr[node], n = cdeg[node];
            if (g == 0) {   // self row (group 0 lanes)
                uint4 v = xu4[(size_t)node * 8 + sseg];
                acc[0] += ulo(v.x); acc[1] += uhi(v.x);
                acc[2] += ulo(v.y); acc[3] += uhi(v.y);
                acc[4] += ulo(v.z); acc[5] += uhi(v.z);
                acc[6] += ulo(v.w); acc[7] += uhi(v.w);
            }
            for (int j0 = 0; j0 < n; j0 += 32) {
                int m = n - j0; if (m > 32) m = 32;
                int ev = (hl < m) ? epk[start + j0 + hl] : 0;
                int j = 0;
                for (; j + 8 <= m; j += 8) {
                    int sa = __shfl(ev, j + g, 32) & 0xffff;
                    int sb = __shfl(ev, j + 4 + g, 32) & 0xffff;
                    uint4 va = xu4[(size_t)sa * 8 + sseg];
                    uint4 vb = xu4[(size_t)sb * 8 + sseg];
                    acc[0] += ulo(va.x); acc[1] += uhi(va.x);
                    acc[2] += ulo(va.y); acc[3] += uhi(va.y);
                    acc[4] += ulo(va.z); acc[5] += uhi(va.z);
                    acc[6] += ulo(va.w); acc[7] += uhi(va.w);
                    acc[0] += ulo(vb.x); acc[1] += uhi(vb.x);
                    acc[2] += ulo(vb.y); acc[3] += uhi(vb.y);
                    acc[4] += ulo(vb.z); acc[5] += uhi(vb.z);
                    acc[6] += ulo(vb.w); acc[7] += uhi(vb.w);
                }
                for (; j < m; j += 4) {
                    int sa = __shfl(ev, j + g, 32) & 0xffff;  // all lanes exec
                    if (g < m - j) {
                        uint4 va = xu4[(size_t)sa * 8 + sseg];
                        acc[0] += ulo(va.x); acc[1] += uhi(va.x);
                        acc[2] += ulo(va.y); acc[3] += uhi(va.y);
                        acc[4] += ulo(va.z); acc[5] += uhi(va.z);
                        acc[6] += ulo(va.w); acc[7] += uhi(va.w);
                    }
                }
            }
        }
        #pragma unroll
        for (int q = 0; q < 8; ++q) {
            acc[q] += __shfl_xor(acc[q], 8, 32);
            acc[q] += __shfl_xor(acc[q], 16, 32);
        }
        if (g == 0) {
            uint4 pv = make_uint4(pack2(acc[0], acc[1]), pack2(acc[2], acc[3]),
                                  pack2(acc[4], acc[5]), pack2(acc[6], acc[7]));
            *(uint4*)(xs + lr * LDWB + sseg * 8) = pv;
        }
    }
    __syncthreads();

    int m = lane & 15, quad = lane >> 4;

    // ---- lin1 (MFMA) + lrelu -> hs
    {
        floatx4 acc = (floatx4){0.f, 0.f, 0.f, 0.f};
        int col = wv * 16 + m;
        #pragma unroll
        for (int ks = 0; ks < 2; ++ks) {
            short8 af = *(const short8*)(xs + m * LDWB + ks * 32 + quad * 8);
            short8 bf = *(const short8*)(waB + (size_t)col * 64 + ks * 32 + quad * 8);
            acc = __builtin_amdgcn_mfma_f32_16x16x32_bf16(af, bf, acc, 0, 0, 0);
        }
        float bias = ba[col];
        #pragma unroll
        for (int r = 0; r < 4; ++r) {
            float v = acc[r] + bias;
            v = v > 0.f ? v : SLOPE * v;
            hs[(quad * 4 + r) * LDWB + col] = f2b(v);
        }
    }
    __syncthreads();

    // ---- lin2 (MFMA)
    {
        floatx4 acc = (floatx4){0.f, 0.f, 0.f, 0.f};
        int col = wv * 16 + m;
        #pragma unroll
        for (int ks = 0; ks < 2; ++ks) {
            short8 af = *(const short8*)(hs + m * LDWB + ks * 32 + quad * 8);
            short8 bf = *(const short8*)(wbB + (size_t)col * 64 + ks * 32 + quad * 8);
            acc = __builtin_amdgcn_mfma_f32_16x16x32_bf16(af, bf, acc, 0, 0, 0);
        }
        float bias = bb[col];
        float ps = 0.f, pq = 0.f;
        #pragma unroll
        for (int r = 0; r < 4; ++r) {
            int node = row0 + quad * 4 + r;
            float v = acc[r] + bias;
            if (node < N_NODES) ybuf[(size_t)node * 64 + col] = v;
            else v = 0.f;
            ps += v; pq += v * v;
        }
        ps += __shfl_xor(ps, 16); pq += __shfl_xor(pq, 16);
        ps += __shfl_xor(ps, 32); pq += __shfl_xor(pq, 32);
        if (quad == 0) {
            float* st = stat_l + (blockIdx.x & (STAT_SHARDS - 1)) * 128;
            atomicAdd(&st[col], ps);
            atomicAdd(&st[64 + col], pq);
        }
    }
}

// ---------------------------------------------------------------------------
// K4: x_out(bf16) = lrelu(y*scale + shift); stats summed over shards
// ---------------------------------------------------------------------------
__global__ void k_bn_apply(const float* __restrict__ y, const float* __restrict__ stat_l,
                           const float* __restrict__ gw, const float* __restrict__ gb,
                           uint_t* __restrict__ xo) {
    __shared__ float sc[64], sh[64];
    int t = threadIdx.x;
    if (t < 64) {
        float s0 = 0.f, q0 = 0.f;
        #pragma unroll
        for (int j = 0; j < STAT_SHARDS; ++j) {
            s0 += stat_l[j * 128 + t];
            q0 += stat_l[j * 128 + 64 + t];
        }
        float mmm = s0 * (1.0f / N_NODES);
        float var = q0 * (1.0f / N_NODES) - mmm * mmm;
        float s = gw[t] * rsqrtf(var + BN_EPS);
        sc[t] = s; sh[t] = gb[t] - mmm * s;
    }
    __syncthreads();
    int idx = blockIdx.x * blockDim.x + t;    // N*16 float4 slots
    if (idx >= N_NODES * 16) return;
    int c4 = (idx & 15) * 4;
    float4 v4 = *(const float4*)(y + (size_t)idx * 4);
    float o0 = v4.x * sc[c4]     + sh[c4];     o0 = o0 > 0.f ? o0 : SLOPE * o0;
    float o1 = v4.y * sc[c4 + 1] + sh[c4 + 1]; o1 = o1 > 0.f ? o1 : SLOPE * o1;
    float o2 = v4.z * sc[c4 + 2] + sh[c4 + 2]; o2 = o2 > 0.f ? o2 : SLOPE * o2;
    float o3 = v4.w * sc[c4 + 3] + sh[c4 + 3]; o3 = o3 > 0.f ? o3 : SLOPE * o3;
    xo[(size_t)idx * 2]     = pack2(o0, o1);
    xo[(size_t)idx * 2 + 1] = pack2(o2, o3);
}

// ---------------------------------------------------------------------------
// K5: fc1 (MFMA), K=320. x3 segment computed INLINE from ybuf (layer-2 pre-BN)
// + stat2 — no third bn_apply. Block touches only its own 16 ybuf rows.
// ---------------------------------------------------------------------------
__global__ __launch_bounds__(256, 8) void k_fc1(
        const uint_t* __restrict__ x0u, const uint_t* __restrict__ x1u,
        const uint_t* __restrict__ x2u, const float* __restrict__ ybuf_in,
        const float* __restrict__ stat2,
        const float* __restrict__ gw2, const float* __restrict__ gb2,
        const ushort_t* __restrict__ wB, const float* __restrict__ b,
        float* __restrict__ ybuf, float* __restrict__ stat_l) {
    constexpr int LDWB = 328;            // ushort stride (320+8), /2=164 uints
    __shared__ ushort_t xs[16 * LDWB];
    __shared__ float sc2[64], sh2[64];
    uint_t* xsu = (uint_t*)xs;
    int t = threadIdx.x;
    int row0 = blockIdx.x * 16;

    if (t < 64) {   // layer-2 BN coefficients from sharded stats
        float s0 = 0.f, q0 = 0.f;
        #pragma unroll
        for (int j = 0; j < STAT_SHARDS; ++j) {
            s0 += stat2[j * 128 + t];
            q0 += stat2[j * 128 + 64 + t];
        }
        float mmm = s0 * (1.0f / N_NODES);
        float var = q0 * (1.0f / N_NODES) - mmm * mmm;
        float s = gw2[t] * rsqrtf(var + BN_EPS);
        sc2[t] = s; sh2[t] = gb2[t] - mmm * s;
    }
    __syncthreads();

    for (int i = t; i < 16 * 160; i += 256) {
        int row = i / 160, c = i % 160;
        int g = row0 + row;
        uint_t v = 0;
        if (g < N_NODES) {
            if      (c < 64)  v = x0u[(size_t)g * 64 + c];
            else if (c < 96)  v = x1u[(size_t)g * 32 + (c - 64)];
            else if (c < 128) v = x2u[(size_t)g * 32 + (c - 96)];
            else {
                int cc = (c - 128) * 2;
                float2 yv = *(const float2*)(ybuf_in + (size_t)g * 64 + cc);
                float o0 = yv.x * sc2[cc]     + sh2[cc];
                float o1 = yv.y * sc2[cc + 1] + sh2[cc + 1];
                o0 = o0 > 0.f ? o0 : SLOPE * o0;
                o1 = o1 > 0.f ? o1 : SLOPE * o1;
                v = pack2(o0, o1);
            }
        }
        xsu[row * 164 + c] = v;
    }
    __syncthreads();

    int lane = t & 63, wv = t >> 6;
    int m = lane & 15, quad = lane >> 4;
    int col = wv * 16 + m;
    floatx4 acc = (floatx4){0.f, 0.f, 0.f, 0.f};
    #pragma unroll
    for (int ks = 0; ks < 10; ++ks) {
        short8 af = *(const short8*)(xs + m * LDWB + ks * 32 + quad * 8);
        short8 bf = *(const short8*)(wB + (size_t)col * 320 + ks * 32 + quad * 8);
        acc = __builtin_amdgcn_mfma_f32_16x16x32_bf16(af, bf, acc, 0, 0, 0);
    }
    float bias = b[col];
    float ps = 0.f, pq = 0.f;
    #pragma unroll
    for (int r = 0; r < 4; ++r) {
        int node = row0 + quad * 4 + r;
        float v = acc[r] + bias;
        if (node < N_NODES) ybuf[(size_t)node * 64 + col] = v;
        else v = 0.f;
        ps += v; pq += v * v;
    }
    ps += __shfl_xor(ps, 16); pq += __shfl_xor(pq, 16);
    ps += __shfl_xor(ps, 32); pq += __shfl_xor(pq, 32);
    if (quad == 0) {
        float* st = stat_l + (blockIdx.x & (STAT_SHARDS - 1)) * 128;
        atomicAdd(&st[col], ps);
        atomicAdd(&st[64 + col], pq);
    }
}

// ---------------------------------------------------------------------------
// K6: out = sigmoid( fc2_w . lrelu(bn(y)) + fc2_b )
// ---------------------------------------------------------------------------
__global__ void k_final(const float* __restrict__ y, const float* __restrict__ stat_l,
                        const float* __restrict__ gw, const float* __restrict__ gb,
                        const float* __restrict__ w2, const float* __restrict__ b2,
                        float* __restrict__ out) {
    __shared__ float sc[64], sh[64], w[64];
    int t = threadIdx.x;
    if (t < 64) {
        float s0 = 0.f, q0 = 0.f;
        #pragma unroll
        for (int j = 0; j < STAT_SHARDS; ++j) {
            s0 += stat_l[j * 128 + t];
            q0 += stat_l[j * 128 + 64 + t];
        }
        float mmm = s0 * (1.0f / N_NODES);
        float var = q0 * (1.0f / N_NODES) - mmm * mmm;
        float s = gw[t] * rsqrtf(var + BN_EPS);
        sc[t] = s; sh[t] = gb[t] - mmm * s; w[t] = w2[t];
    }
    __syncthreads();
    int i = blockIdx.x * blockDim.x + t;
    if (i >= N_NODES) return;
    float z = b2[0];
    const float* row = y + (size_t)i * 64;
    #pragma unroll
    for (int c = 0; c < 64; c += 4) {
        float4 v4 = *(const float4*)(row + c);
        float v;
        v = v4.x * sc[c]   + sh[c];   v = v > 0.f ? v : SLOPE * v; z += v * w[c];
        v = v4.y * sc[c+1] + sh[c+1]; v = v > 0.f ? v : SLOPE * v; z += v * w[c+1];
        v = v4.z * sc[c+2] + sh[c+2]; v = v > 0.f ? v : SLOPE * v; z += v * w[c+2];
        v = v4.w * sc[c+3] + sh[c+3]; v = v > 0.f ? v : SLOPE * v; z += v * w[c+3];
    }
    out[i] = 1.f / (1.f + __expf(-z));
}

// ---------------------------------------------------------------------------
extern "C" void kernel_launch(void* const* d_in, const int* in_sizes, int n_in,
                              void* d_out, int out_size, void* d_ws, size_t ws_size,
                              hipStream_t stream) {
    const float* emb_deg = (const float*)d_in[0];
    const float* emb_lab = (const float*)d_in[1];
    const float* wA[3]  = {(const float*)d_in[2],  (const float*)d_in[8],  (const float*)d_in[14]};
    const float* bA[3]  = {(const float*)d_in[3],  (const float*)d_in[9],  (const float*)d_in[15]};
    const float* wB[3]  = {(const float*)d_in[4],  (const float*)d_in[10], (const float*)d_in[16]};
    const float* bB[3]  = {(const float*)d_in[5],  (const float*)d_in[11], (const float*)d_in[17]};
    const float* bnw[3] = {(const float*)d_in[6],  (const float*)d_in[12], (const float*)d_in[18]};
    const float* bnb[3] = {(const float*)d_in[7],  (const float*)d_in[13], (const float*)d_in[19]};
    const float* fc1_w  = (const float*)d_in[20];
    const float* fc1_b  = (const float*)d_in[21];
    const float* fcbn_w = (const float*)d_in[22];
    const float* fcbn_b = (const float*)d_in[23];
    const float* fc2_w  = (const float*)d_in[24];
    const float* fc2_b  = (const float*)d_in[25];
    const int* node_deg = (const int*)d_in[26];
    const int* node_lab = (const int*)d_in[27];
    const int* src = (const int*)d_in[28];
    const int* dst = src + E_EDGES;
    float* out = (float*)d_out;

    // workspace layout
    float* ws   = (float*)d_ws;
    float* ybf  = ws;                                  // N*64 fp32
    float* stat = ybf + (size_t)N_NODES * 64;          // 4 * 32 * 128 floats
    uint_t* x0u = (uint_t*)(stat + 4 * STAT_SHARDS * 128);  // N*64 uints
    uint_t* x1u = x0u + (size_t)N_NODES * 64;          // N*32
    uint_t* x2u = x1u + (size_t)N_NODES * 32;          // N*32
    int* epk    = (int*)(x2u + (size_t)N_NODES * 32);  // E packed edges
    int* rank   = epk + E_EDGES;                       // E
    ushort_t* wbf = (ushort_t*)(rank + E_EDGES);       // WTOT bf16
    ushort_t* Ptb = wbf + WTOT;                        // 128*96 bf16
    int* cdeg   = (int*)(Ptb + 128 * 96);              // N
    int* rowptr = cdeg + N_NODES;
    int* ncls   = rowptr + N_NODES;
    int* bsum   = ncls + N_NODES;                      // SCAN_BLOCKS

    const int RB = (N_NODES + 15) / 16;            // 3125 row-tile blocks
    const int VB = (N_NODES * 16 + 255) / 256;     // 3125 float4 elementwise blocks
    const int HB = (N_NODES * 64 + 255) / 256;     // 12500 build-x0 blocks
    const int NB = (N_NODES + 255) / 256;          // 196 node blocks

    // R14-proven front-end order
    hipMemsetAsync(stat, 0, (size_t)(4 * STAT_SHARDS * 128) * sizeof(float), stream);
    hipMemsetAsync(cdeg, 0, (size_t)N_NODES * sizeof(int), stream);

    k_prep<<<CVT_BLOCKS + P_BLOCKS, 256, 0, stream>>>(wA[0], wB[0], wA[1], wB[1],
        wA[2], wB[2], fc1_w, wbf, emb_deg, emb_lab, Ptb);
    k_build_x0<<<HB, 256, 0, stream>>>(emb_deg, emb_lab, node_deg, node_lab, x0u, ncls);

    k_degrank<<<E_BLOCKS, 256, 0, stream>>>(dst, cdeg, rank);
    k_scan_a<<<SCAN_BLOCKS, 256, 0, stream>>>(cdeg, bsum);
    k_scan_c<<<SCAN_BLOCKS, 256, 0, stream>>>(cdeg, bsum, rowptr);
    k_fill<<<FILL_PASSES * E_BLOCKS, 256, 0, stream>>>(src, dst, ncls, rowptr,
                                                       rank, epk, E_BLOCKS);

    // ---- layer 0: LDS-histogram + dense MFMA
    k_mlp0<<<RB, 256, 0, stream>>>(rowptr, cdeg, epk, ncls, Ptb, bA[0],
                                   wbf + OWB0, bB[0], ybf, stat);
    k_bn_apply<<<VB, 256, 0, stream>>>(ybf, stat, bnw[0], bnb[0], x1u);

    // ---- layer 1
    k_mlp64<<<RB, 256, 0, stream>>>((const ushort_t*)x1u, rowptr, cdeg, epk,
        wbf + OWA1, bA[1], wbf + OWB1, bB[1], ybf, stat + STAT_SHARDS * 128);
    k_bn_apply<<<VB, 256, 0, stream>>>(ybf, stat + STAT_SHARDS * 128,
                                       bnw[1], bnb[1], x2u);

    // ---- layer 2 (BN fused into fc1)
    k_mlp64<<<RB, 256, 0, stream>>>((const ushort_t*)x2u, rowptr, cdeg, epk,
        wbf + OWA2, bA[2], wbf + OWB2, bB[2], ybf, stat + 2 * STAT_SHARDS * 128);

    float* stf = stat + 3 * STAT_SHARDS * 128;
    k_fc1<<<RB, 256, 0, stream>>>(x0u, x1u, x2u, ybf, stat + 2 * STAT_SHARDS * 128,
        bnw[2], bnb[2], wbf + OFC1, fc1_b, ybf, stf);
    k_final<<<NB, 256, 0, stream>>>(ybf, stf, fcbn_w, fcbn_b, fc2_w, fc2_b, out);
}